// Round 6
// baseline (532.446 us; speedup 1.0000x reference)
//
#include <hip/hip_runtime.h>
#include <math.h>
#include <float.h>

#define NNODES 50000
#define NPAD   50048   // 782*64, rows the MFMA gemm may touch
#define NEDGES 800000
#define NBLK 196       // ceil(50000/256)
// D = 128 fixed

typedef __attribute__((ext_vector_type(8))) short bfrag;   // 8 bf16 (4 VGPR)
typedef __attribute__((ext_vector_type(4))) float ffrag;   // 4 fp32 acc

// ---------------------------------------------------------------- bf16 split
// v ~= hi + lo, both RN-bf16. |v - hi - lo| <~ 2^-17 |v|.
static __device__ __forceinline__ void bsplit(float f, ushort& h, ushort& l) {
  unsigned u = __float_as_uint(f);
  unsigned hb = (u + 0x7FFFu + ((u >> 16) & 1u)) >> 16;
  h = (ushort)hb;
  float r = f - __uint_as_float(hb << 16);
  unsigned v = __float_as_uint(r);
  l = (ushort)((v + 0x7FFFu + ((v >> 16) & 1u)) >> 16);
}

// --------------------------------------------- W -> bf16 planes (row-major)
// B layout per layer: rows 0..127 = Wl[n][k], rows 128..255 = Wr[n][k].
__global__ __launch_bounds__(256) void convert_w(
    const float* __restrict__ w0, const float* __restrict__ w1,
    const float* __restrict__ w2, const float* __restrict__ w3,
    const float* __restrict__ w4, const float* __restrict__ w5,
    ushort* __restrict__ bhi, ushort* __restrict__ blo)
{
  int g = blockIdx.x * 256 + threadIdx.x;   // 0..98303
  int mat = g >> 14;                        // 0..5 : Wl0,Wr0,Wl1,Wr1,Wl2,Wr2
  int r = g & 16383;
  const float* s = w0;
  if (mat == 1) s = w1; else if (mat == 2) s = w2; else if (mat == 3) s = w3;
  else if (mat == 4) s = w4; else if (mat == 5) s = w5;
  ushort h, l;
  bsplit(s[r], h, l);
  int o = (mat >> 1) * 32768 + (mat & 1) * 16384 + r;
  bhi[o] = h;
  blo[o] = l;
}

// --------------------------------------------- x -> bf16 planes (row-major)
__global__ __launch_bounds__(256) void convert_x(
    const float* __restrict__ x, ushort* __restrict__ ahi,
    ushort* __restrict__ alo)
{
  int idx = blockIdx.x * 256 + threadIdx.x;      // over 50000*32 float4s
  if (idx >= NNODES * 32) return;
  float4 v = ((const float4*)x)[idx];
  ushort h0,l0,h1,l1,h2,l2,h3,l3;
  bsplit(v.x, h0, l0); bsplit(v.y, h1, l1);
  bsplit(v.z, h2, l2); bsplit(v.w, h3, l3);
  ushort4 hv = {h0, h1, h2, h3};
  ushort4 lv = {l0, l1, l2, l3};
  ((ushort4*)ahi)[idx] = hv;
  ((ushort4*)alo)[idx] = lv;
}

// ------------------------------------------------------------- CSR build
// Harness uploads integer inputs as int32 — edge_index is const int*.
__global__ __launch_bounds__(256) void hist_kernel(
    const int* __restrict__ ei, int* __restrict__ counts)
{
  int e = blockIdx.x * 256 + threadIdx.x;
  if (e < NEDGES) {
    int d = ei[NEDGES + e];
    atomicAdd(&counts[d], 1);
  }
}

__global__ __launch_bounds__(256) void scan_part(
    const int* __restrict__ counts, int* __restrict__ part,
    int* __restrict__ bsum)
{
  __shared__ int sh[256];
  int t = threadIdx.x;
  int i = blockIdx.x * 256 + t;
  int v = (i < NNODES) ? counts[i] + 1 : 0;   // +1 = self loop slot
  sh[t] = v;
  __syncthreads();
  for (int off = 1; off < 256; off <<= 1) {
    int u = (t >= off) ? sh[t - off] : 0;
    __syncthreads();
    sh[t] += u;
    __syncthreads();
  }
  if (i < NNODES) part[i] = sh[t] - v;
  if (t == 255) bsum[blockIdx.x] = sh[255];
}

__global__ __launch_bounds__(256) void scan_bsums(int* __restrict__ bsum)
{
  __shared__ int sh[256];
  int t = threadIdx.x;
  int v = (t < NBLK) ? bsum[t] : 0;
  sh[t] = v;
  __syncthreads();
  for (int off = 1; off < 256; off <<= 1) {
    int u = (t >= off) ? sh[t - off] : 0;
    __syncthreads();
    sh[t] += u;
    __syncthreads();
  }
  if (t < NBLK) bsum[t] = sh[t] - v;
}

__global__ __launch_bounds__(256) void scan_final(
    const int* __restrict__ part, const int* __restrict__ bsum,
    int* __restrict__ rowptr, int* __restrict__ cursor)
{
  int i = blockIdx.x * 256 + threadIdx.x;
  if (i < NNODES) {
    int r = part[i] + bsum[blockIdx.x];
    rowptr[i] = r;
    cursor[i] = r;
  }
  if (i == 0) rowptr[NNODES] = NEDGES + NNODES;
}

__global__ __launch_bounds__(256) void scatter_kernel(
    const int* __restrict__ ei, int* __restrict__ cursor,
    int* __restrict__ col)
{
  int e = blockIdx.x * 256 + threadIdx.x;
  if (e < NEDGES + NNODES) {
    int s, d;
    if (e < NEDGES) { s = ei[e]; d = ei[NEDGES + e]; }
    else           { s = e - NEDGES; d = s; }   // self loop
    int slot = atomicAdd(&cursor[d], 1);
    col[slot] = s;
  }
}

// ------------------------------------------------- MFMA split-bf16 dual GEMM
// xl[m][n] = sum_k h[m][k] Wl[n][k]; xr likewise; one M x 256 GEMM with
// B = [Wl ; Wr], C = Ah.Bh + Ah.Bl + Al.Bh (fp32 acc, Al.Bl dropped).
__global__ __launch_bounds__(256) void gemm_mfma(
    const ushort* __restrict__ ahi, const ushort* __restrict__ alo,
    const ushort* __restrict__ bhi, const ushort* __restrict__ blo,
    float* __restrict__ xl, float* __restrict__ xr)
{
  const int wave = threadIdx.x >> 6;
  const int lane = threadIdx.x & 63;
  const int l16  = lane & 15;
  const int kq   = lane >> 4;              // 0..3
  const int m0   = blockIdx.x * 64;

  ffrag acc[4][4];
#pragma unroll
  for (int mt = 0; mt < 4; ++mt)
#pragma unroll
    for (int nt = 0; nt < 4; ++nt)
      acc[mt][nt] = (ffrag){0.f, 0.f, 0.f, 0.f};

#pragma unroll
  for (int kb = 0; kb < 4; ++kb) {
    const int k0 = kb * 32 + kq * 8;
    bfrag ah[4], al[4], bh[4], bl[4];
#pragma unroll
    for (int mt = 0; mt < 4; ++mt) {
      int m = m0 + mt * 16 + l16;          // < NPAD (planes padded)
      ah[mt] = *(const bfrag*)&ahi[m * 128 + k0];
      al[mt] = *(const bfrag*)&alo[m * 128 + k0];
    }
#pragma unroll
    for (int nt = 0; nt < 4; ++nt) {
      int n = wave * 64 + nt * 16 + l16;   // 0..255
      bh[nt] = *(const bfrag*)&bhi[n * 128 + k0];
      bl[nt] = *(const bfrag*)&blo[n * 128 + k0];
    }
#pragma unroll
    for (int mt = 0; mt < 4; ++mt)
#pragma unroll
      for (int nt = 0; nt < 4; ++nt) {
        acc[mt][nt] = __builtin_amdgcn_mfma_f32_16x16x32_bf16(
            ah[mt], bh[nt], acc[mt][nt], 0, 0, 0);
        acc[mt][nt] = __builtin_amdgcn_mfma_f32_16x16x32_bf16(
            ah[mt], bl[nt], acc[mt][nt], 0, 0, 0);
        acc[mt][nt] = __builtin_amdgcn_mfma_f32_16x16x32_bf16(
            al[mt], bh[nt], acc[mt][nt], 0, 0, 0);
      }
  }

#pragma unroll
  for (int mt = 0; mt < 4; ++mt) {
    int mb = m0 + mt * 16 + kq * 4;
#pragma unroll
    for (int nt = 0; nt < 4; ++nt) {
      int ng = wave * 64 + nt * 16 + l16;
      float* dst = (ng < 128) ? xl : xr;
      int n = ng & 127;
#pragma unroll
      for (int r = 0; r < 4; ++r) {
        int m = mb + r;
        if (m < NNODES) dst[m * 128 + n] = acc[mt][nt][r];
      }
    }
  }
}

// ---------------------------------------- fused attention + aggregate + GELU
// One wave per dst node, two 32-lane halves. Each half consumes 4-edge chunks
// (chunks alternate between halves), 4 feats/lane float4 gathers.
// DEFERRED-MAX online softmax: per-half reference m rescaled only when a
// logit exceeds m+60 (softmax is shift-invariant; e^60 can't overflow the
// fp32 accumulators). Common path = ONE exp + independent adds per edge.
__global__ __launch_bounds__(256) void agg_kernel(
    const int* __restrict__ rowptr, const int* __restrict__ col,
    const float* __restrict__ xl, const float* __restrict__ xr,
    const float* __restrict__ att, const float* __restrict__ bias,
    float* __restrict__ hout, ushort* __restrict__ ahi,
    ushort* __restrict__ alo, int last)
{
  const int tid  = threadIdx.x;
  const int lane = tid & 63;
  const int half = lane >> 5;
  const int l32  = lane & 31;
  const int d    = blockIdx.x * 4 + (tid >> 6);

  const float4* xl4 = (const float4*)xl;
  float4 xrv = ((const float4*)xr)[d * 32 + l32];
  float4 av  = ((const float4*)att)[l32];
  int beg = rowptr[d], end = rowptr[d + 1];

  float m = -FLT_MAX;                     // per-half softmax reference
  float dn0 = 0.f, dn1 = 0.f;             // 2 accumulator states (ILP)
  float4 a0 = {0.f,0.f,0.f,0.f}, a1 = {0.f,0.f,0.f,0.f};

  int k0 = beg + 4 * half;                // this half's chunks: k0, k0+8, ...
  for (; k0 + 3 < end; k0 += 8) {
    int c0 = col[k0], c1 = col[k0+1], c2 = col[k0+2], c3 = col[k0+3];
    float4 v0 = xl4[c0 * 32 + l32];
    float4 v1 = xl4[c1 * 32 + l32];
    float4 v2 = xl4[c2 * 32 + l32];
    float4 v3 = xl4[c3 * 32 + l32];

    float4 t0, t1, t2, t3;
    t0.x = v0.x + xrv.x; t0.y = v0.y + xrv.y; t0.z = v0.z + xrv.z; t0.w = v0.w + xrv.w;
    t1.x = v1.x + xrv.x; t1.y = v1.y + xrv.y; t1.z = v1.z + xrv.z; t1.w = v1.w + xrv.w;
    t2.x = v2.x + xrv.x; t2.y = v2.y + xrv.y; t2.z = v2.z + xrv.z; t2.w = v2.w + xrv.w;
    t3.x = v3.x + xrv.x; t3.y = v3.y + xrv.y; t3.z = v3.z + xrv.z; t3.w = v3.w + xrv.w;
    t0.x = fmaxf(t0.x, 0.2f*t0.x); t0.y = fmaxf(t0.y, 0.2f*t0.y);
    t0.z = fmaxf(t0.z, 0.2f*t0.z); t0.w = fmaxf(t0.w, 0.2f*t0.w);
    t1.x = fmaxf(t1.x, 0.2f*t1.x); t1.y = fmaxf(t1.y, 0.2f*t1.y);
    t1.z = fmaxf(t1.z, 0.2f*t1.z); t1.w = fmaxf(t1.w, 0.2f*t1.w);
    t2.x = fmaxf(t2.x, 0.2f*t2.x); t2.y = fmaxf(t2.y, 0.2f*t2.y);
    t2.z = fmaxf(t2.z, 0.2f*t2.z); t2.w = fmaxf(t2.w, 0.2f*t2.w);
    t3.x = fmaxf(t3.x, 0.2f*t3.x); t3.y = fmaxf(t3.y, 0.2f*t3.y);
    t3.z = fmaxf(t3.z, 0.2f*t3.z); t3.w = fmaxf(t3.w, 0.2f*t3.w);
    float q0 = fmaf(t0.x, av.x, fmaf(t0.y, av.y, fmaf(t0.z, av.z, t0.w*av.w)));
    float q1 = fmaf(t1.x, av.x, fmaf(t1.y, av.y, fmaf(t1.z, av.z, t1.w*av.w)));
    float q2 = fmaf(t2.x, av.x, fmaf(t2.y, av.y, fmaf(t2.z, av.z, t2.w*av.w)));
    float q3 = fmaf(t3.x, av.x, fmaf(t3.y, av.y, fmaf(t3.z, av.z, t3.w*av.w)));
#pragma unroll
    for (int off = 16; off > 0; off >>= 1) {  // 4 independent chains
      q0 += __shfl_xor(q0, off, 64);
      q1 += __shfl_xor(q1, off, 64);
      q2 += __shfl_xor(q2, off, 64);
      q3 += __shfl_xor(q3, off, 64);
    }
    float qm = fmaxf(fmaxf(q0, q1), fmaxf(q2, q3));
    if (qm > m + 60.f) {                   // rare (first chunk, then ~never)
      float sc = __expf(m - qm);           // m=-FLT_MAX -> 0: zeroes zeros
      dn0 *= sc; dn1 *= sc;
      a0.x *= sc; a0.y *= sc; a0.z *= sc; a0.w *= sc;
      a1.x *= sc; a1.y *= sc; a1.z *= sc; a1.w *= sc;
      m = qm;
    }
    float w0 = __expf(q0 - m), w1 = __expf(q1 - m);
    float w2 = __expf(q2 - m), w3 = __expf(q3 - m);
    dn0 += w0 + w2;
    dn1 += w1 + w3;
    a0.x = fmaf(w0, v0.x, fmaf(w2, v2.x, a0.x));
    a0.y = fmaf(w0, v0.y, fmaf(w2, v2.y, a0.y));
    a0.z = fmaf(w0, v0.z, fmaf(w2, v2.z, a0.z));
    a0.w = fmaf(w0, v0.w, fmaf(w2, v2.w, a0.w));
    a1.x = fmaf(w1, v1.x, fmaf(w3, v3.x, a1.x));
    a1.y = fmaf(w1, v1.y, fmaf(w3, v3.y, a1.y));
    a1.z = fmaf(w1, v1.z, fmaf(w3, v3.z, a1.z));
    a1.w = fmaf(w1, v1.w, fmaf(w3, v3.w, a1.w));
  }
  if (k0 < end) {                          // tail: up to 4 masked edges
    for (int k = k0; k < k0 + 4; ++k) {
      bool va = k < end;
      int c = col[va ? k : beg];
      float4 v = xl4[c * 32 + l32];
      float4 t;
      t.x = v.x + xrv.x; t.y = v.y + xrv.y; t.z = v.z + xrv.z; t.w = v.w + xrv.w;
      t.x = fmaxf(t.x, 0.2f*t.x); t.y = fmaxf(t.y, 0.2f*t.y);
      t.z = fmaxf(t.z, 0.2f*t.z); t.w = fmaxf(t.w, 0.2f*t.w);
      float q = fmaf(t.x, av.x, fmaf(t.y, av.y, fmaf(t.z, av.z, t.w*av.w)));
#pragma unroll
      for (int off = 16; off > 0; off >>= 1) q += __shfl_xor(q, off, 64);
      if (va) {
        if (q > m + 60.f) {
          float sc = __expf(m - q);
          dn0 *= sc; dn1 *= sc;
          a0.x *= sc; a0.y *= sc; a0.z *= sc; a0.w *= sc;
          a1.x *= sc; a1.y *= sc; a1.z *= sc; a1.w *= sc;
          m = q;
        }
        float w = __expf(q - m);
        dn0 += w;
        a0.x = fmaf(w, v.x, a0.x); a0.y = fmaf(w, v.y, a0.y);
        a0.z = fmaf(w, v.z, a0.z); a0.w = fmaf(w, v.w, a0.w);
      }
    }
  }

  // intra-half: states share m -> plain adds
  float dn = dn0 + dn1;
  float4 ac;
  ac.x = a0.x + a1.x; ac.y = a0.y + a1.y;
  ac.z = a0.z + a1.z; ac.w = a0.w + a1.w;

  // merge across halves (xor 32); empty half has m=-FLT_MAX -> weight 0
  float Mo  = __shfl_xor(m, 32, 64);
  float dno = __shfl_xor(dn, 32, 64);
  float aox = __shfl_xor(ac.x, 32, 64);
  float aoy = __shfl_xor(ac.y, 32, 64);
  float aoz = __shfl_xor(ac.z, 32, 64);
  float aow = __shfl_xor(ac.w, 32, 64);
  float M  = fmaxf(m, Mo);
  float eA = __expf(m - M), eB = __expf(Mo - M);
  float den = dn * eA + dno * eB;
  float inv = 1.f / den;
  float4 bi = ((const float4*)bias)[l32];
  float o0 = fmaf((ac.x * eA + aox * eB), inv, bi.x);
  float o1 = fmaf((ac.y * eA + aoy * eB), inv, bi.y);
  float o2 = fmaf((ac.z * eA + aoz * eB), inv, bi.z);
  float o3 = fmaf((ac.w * eA + aow * eB), inv, bi.w);
  o0 = 0.5f * o0 * (1.f + erff(o0 * 0.70710678118654752f));
  o1 = 0.5f * o1 * (1.f + erff(o1 * 0.70710678118654752f));
  o2 = 0.5f * o2 * (1.f + erff(o2 * 0.70710678118654752f));
  o3 = 0.5f * o3 * (1.f + erff(o3 * 0.70710678118654752f));
  if (half == 0) {
    if (last) {
      ((float4*)hout)[d * 32 + l32] = make_float4(o0, o1, o2, o3);
    } else {
      ushort h0,l0,h1,l1,h2,l2,h3,l3;
      bsplit(o0, h0, l0); bsplit(o1, h1, l1);
      bsplit(o2, h2, l2); bsplit(o3, h3, l3);
      ushort4 hv = {h0, h1, h2, h3};
      ushort4 lv = {l0, l1, l2, l3};
      ((ushort4*)ahi)[d * 32 + l32] = hv;
      ((ushort4*)alo)[d * 32 + l32] = lv;
    }
  }
}

// ------------------------------------------------------------------ launch
extern "C" void kernel_launch(void* const* d_in, const int* in_sizes, int n_in,
                              void* d_out, int out_size, void* d_ws, size_t ws_size,
                              hipStream_t stream)
{
  const float* x = (const float*)d_in[0];
  const int* ei = (const int*)d_in[1];     // int inputs arrive as int32
  const float *Wl[3], *Wr[3], *attv[3], *bv[3];
  for (int l = 0; l < 3; ++l) {
    Wl[l]   = (const float*)d_in[2 + 4 * l];
    Wr[l]   = (const float*)d_in[3 + 4 * l];
    attv[l] = (const float*)d_in[4 + 4 * l];
    bv[l]   = (const float*)d_in[5 + 4 * l];
  }

  char* base = (char*)d_ws;
  size_t off = 0;
  auto alloc = [&](size_t bytes) -> char* {
    char* p = base + off;
    off += (bytes + 255) & ~(size_t)255;
    return p;
  };
  ushort* ahi  = (ushort*)alloc((size_t)NPAD * 128 * 2);   // 12.8 MB
  ushort* alo  = (ushort*)alloc((size_t)NPAD * 128 * 2);
  ushort* bhi  = (ushort*)alloc((size_t)3 * 256 * 128 * 2); // 196 KB
  ushort* blo  = (ushort*)alloc((size_t)3 * 256 * 128 * 2);
  float* xl    = (float*)alloc((size_t)NNODES * 128 * 4);  // 25.6 MB
  int* rowptr  = (int*)alloc((size_t)(NNODES + 1) * 4);
  int* cursor  = (int*)alloc((size_t)NNODES * 4);
  int* counts  = (int*)alloc((size_t)NNODES * 4);
  int* part    = (int*)alloc((size_t)(NBLK * 256) * 4);
  int* bsum    = (int*)alloc((size_t)256 * 4);
  int* col     = (int*)alloc((size_t)(NEDGES + NNODES) * 4);
  float* xr    = (float*)d_out;   // aliased: agg wave reads its xr row before
                                  // writing the same row; no cross-row hazard.
  (void)ws_size; (void)in_sizes; (void)n_in; (void)out_size;

  hipMemsetAsync(counts, 0, (size_t)NNODES * 4, stream);
  convert_w<<<384, 256, 0, stream>>>(Wl[0], Wr[0], Wl[1], Wr[1], Wl[2], Wr[2],
                                     bhi, blo);
  convert_x<<<(NNODES * 32 + 255) / 256, 256, 0, stream>>>(x, ahi, alo);
  hist_kernel<<<(NEDGES + 255) / 256, 256, 0, stream>>>(ei, counts);
  scan_part<<<NBLK, 256, 0, stream>>>(counts, part, bsum);
  scan_bsums<<<1, 256, 0, stream>>>(bsum);
  scan_final<<<NBLK, 256, 0, stream>>>(part, bsum, rowptr, cursor);
  scatter_kernel<<<(NEDGES + NNODES + 255) / 256, 256, 0, stream>>>(ei, cursor, col);

  for (int l = 0; l < 3; ++l) {
    gemm_mfma<<<NPAD / 64, 256, 0, stream>>>(
        ahi, alo, bhi + (size_t)l * 32768, blo + (size_t)l * 32768, xl, xr);
    agg_kernel<<<NNODES / 4, 256, 0, stream>>>(
        rowptr, col, xl, xr, attv[l], bv[l], (float*)d_out, ahi, alo,
        (l == 2) ? 1 : 0);
  }
}